// Round 1
// baseline (1006.805 us; speedup 1.0000x reference)
//
#include <hip/hip_runtime.h>
#include <cstdint>
#include <cstddef>

// ---------------------------------------------------------------------------
// MultiHeadSelfAttention: x(64,64,4096) fp32; W q/k/v/o (4096,4096); quirky RoPE
// Pipeline: cast->f16 | GEMM qkv (M4096,N12288,K4096) | fused rope+flash-attn
//           per (b,h) | GEMM out-proj -> fp32 d_out
// All MFMA f16 16x16x32, fp32 accumulate.
// ---------------------------------------------------------------------------

typedef _Float16 half8 __attribute__((ext_vector_type(8)));
typedef float floatx4 __attribute__((ext_vector_type(4)));

#define D_MODEL 4096
#define ROWS    4096            // B*S
#define NEG_LOG2_10000_OVER_2048 (-0.0064881408103278559f)

// async global->LDS, 16 bytes per lane
__device__ __forceinline__ void gl_lds16(const void* g, void* l) {
    __builtin_amdgcn_global_load_lds(
        (const __attribute__((address_space(1))) void*)(void*)g,
        (__attribute__((address_space(3))) void*)l,
        16, 0, 0);
}

// ---------------------------------------------------------------------------
// fp32 -> f16 cast, 8 elements/thread/iter
// ---------------------------------------------------------------------------
__global__ __launch_bounds__(256) void cast_f16_kernel(
    const float* __restrict__ s, _Float16* __restrict__ d, int n)
{
    int i0 = (blockIdx.x * 256 + threadIdx.x) * 8;
    int stride = gridDim.x * 256 * 8;
    for (int i = i0; i < n; i += stride) {
        const float4 a = *(const float4*)(s + i);
        const float4 b = *(const float4*)(s + i + 4);
        half8 h;
        h[0] = (_Float16)a.x; h[1] = (_Float16)a.y;
        h[2] = (_Float16)a.z; h[3] = (_Float16)a.w;
        h[4] = (_Float16)b.x; h[5] = (_Float16)b.y;
        h[6] = (_Float16)b.z; h[7] = (_Float16)b.w;
        *(half8*)(d + i) = h;
    }
}

// ---------------------------------------------------------------------------
// NT GEMM: C[m,n] = sum_k A[m,k]*B[n,k] + bias[n]
// A: MxK f16 row-major, B: NxK f16 row-major. 128x128 tile, BK=32.
// 4 waves, each 64x64 (4x4 tiles of 16x16x32 f16 MFMA).
// OUT_F16=1 -> f16 out, else fp32 out.
// ---------------------------------------------------------------------------
template <int OUT_F16>
__global__ __launch_bounds__(256, 2) void gemm_nt_kernel(
    const _Float16* __restrict__ A, const _Float16* __restrict__ B,
    const float* __restrict__ bias, void* __restrict__ Cout,
    int M, int N, int K)
{
    __shared__ __align__(16) _Float16 As[128 * 32];
    __shared__ __align__(16) _Float16 Bs[128 * 32];

    const int tid  = threadIdx.x;
    const int col0 = blockIdx.x * 128;
    const int row0 = blockIdx.y * 128;
    const int wave = tid >> 6;
    const int lane = tid & 63;
    const int wm = (wave >> 1) * 64;   // wave row offset in tile
    const int wn = (wave & 1) * 64;    // wave col offset in tile

    floatx4 zero = {0.f, 0.f, 0.f, 0.f};
    floatx4 acc[4][4];
#pragma unroll
    for (int i = 0; i < 4; i++)
#pragma unroll
        for (int j = 0; j < 4; j++) acc[i][j] = zero;

    // staging: thread t covers (row = t>>2, cols (t&3)*8 .. +8) of the k-tile
    const int ar = tid >> 2;
    const int ac = (tid & 3) * 8;
    const _Float16* Ag0 = A + (size_t)(row0 + ar) * K + ac;
    const _Float16* Ag1 = A + (size_t)(row0 + 64 + ar) * K + ac;
    const _Float16* Bg0 = B + (size_t)(col0 + ar) * K + ac;
    const _Float16* Bg1 = B + (size_t)(col0 + 64 + ar) * K + ac;
    _Float16* As0 = As + tid * 8;
    _Float16* As1 = As + (tid + 256) * 8;
    _Float16* Bs0 = Bs + tid * 8;
    _Float16* Bs1 = Bs + (tid + 256) * 8;

    const int fr = lane & 15;          // fragment row (m) / col (n)
    const int fc = (lane >> 4) * 8;    // k-chunk within BK=32

    for (int kt = 0; kt < K; kt += 32) {
        gl_lds16(Ag0 + kt, As0);
        gl_lds16(Ag1 + kt, As1);
        gl_lds16(Bg0 + kt, Bs0);
        gl_lds16(Bg1 + kt, Bs1);
        __syncthreads();

        half8 af[4], bf[4];
#pragma unroll
        for (int t = 0; t < 4; t++) {
            af[t] = *(const half8*)(As + (size_t)(wm + t * 16 + fr) * 32 + fc);
            bf[t] = *(const half8*)(Bs + (size_t)(wn + t * 16 + fr) * 32 + fc);
        }
#pragma unroll
        for (int i = 0; i < 4; i++)
#pragma unroll
            for (int j = 0; j < 4; j++)
                acc[i][j] = __builtin_amdgcn_mfma_f32_16x16x32_f16(
                    af[i], bf[j], acc[i][j], 0, 0, 0);
        __syncthreads();
    }

    // epilogue: C/D layout col=lane&15, row=(lane>>4)*4+reg
    const int crow = row0 + wm + ((lane >> 4) << 2);
    const int ccol = col0 + wn + (lane & 15);
#pragma unroll
    for (int i = 0; i < 4; i++) {
#pragma unroll
        for (int j = 0; j < 4; j++) {
            const int gc = ccol + j * 16;
            const float bv = bias[gc];
#pragma unroll
            for (int r2 = 0; r2 < 4; r2++) {
                const int gr = crow + i * 16 + r2;
                const float v = acc[i][j][r2] + bv;
                if (OUT_F16)
                    ((_Float16*)Cout)[(size_t)gr * N + gc] = (_Float16)v;
                else
                    ((float*)Cout)[(size_t)gr * N + gc] = v;
            }
        }
    }
}

// ---------------------------------------------------------------------------
// Fused rope + attention. One block per (b,h). qkv: (4096, 12288) f16,
// q at col h*64+d, k at 4096+h*64+d, v at 8192+h*64+d. out: (4096,4096) f16.
// RoPE quirk: theta = b * 10000^(-(s*32 + d/2)/2048).
// ---------------------------------------------------------------------------
__global__ __launch_bounds__(256) void attn_kernel(
    const _Float16* __restrict__ qkv, _Float16* __restrict__ out)
{
    __shared__ __align__(16) _Float16 qs[64][72];
    __shared__ __align__(16) _Float16 ks[64][72];
    __shared__ __align__(16) _Float16 vt[64][72];   // vt[d][s_k]
    __shared__ __align__(16) _Float16 ps[4][16][72];

    const int tid  = threadIdx.x;
    const int bb   = blockIdx.x >> 6;   // batch
    const int hh   = blockIdx.x & 63;   // head
    const int wave = tid >> 6;
    const int lane = tid & 63;
    const int r  = tid >> 2;            // row s, 0..63
    const int cb = (tid & 3) * 8;       // col base within 32-chunk
    const float fb = (float)bb;

    const _Float16* grow = qkv + (size_t)(bb * 64 + r) * 12288 + hh * 64;

#pragma unroll
    for (int u = 0; u < 2; u++) {
        const int c8 = cb + u * 32;     // contiguous 32-col chunks per 4-lane group
        half8 q8 = *(const half8*)(grow + c8);
        half8 k8 = *(const half8*)(grow + 4096 + c8);
        half8 v8 = *(const half8*)(grow + 8192 + c8);
#pragma unroll
        for (int p = 0; p < 4; p++) {
            const int m = r * 32 + (c8 >> 1) + p;
            const float theta = fb * exp2f((float)m * NEG_LOG2_10000_OVER_2048);
            float sn, cs;
            __sincosf(theta, &sn, &cs);
            const float qe = (float)q8[2 * p], qo = (float)q8[2 * p + 1];
            q8[2 * p]     = (_Float16)(qe * cs - qo * sn);
            q8[2 * p + 1] = (_Float16)(qe * sn + qo * cs);
            const float ke = (float)k8[2 * p], ko = (float)k8[2 * p + 1];
            k8[2 * p]     = (_Float16)(ke * cs - ko * sn);
            k8[2 * p + 1] = (_Float16)(ke * sn + ko * cs);
        }
        *(half8*)&qs[r][c8] = q8;
        *(half8*)&ks[r][c8] = k8;
#pragma unroll
        for (int j = 0; j < 8; j++) vt[c8 + j][r] = v8[j];
    }
    __syncthreads();

    const int fr = lane & 15;
    const int fc = (lane >> 4) * 8;

    // scores: wave handles rows sq in [wave*16, wave*16+16), all 64 cols
    floatx4 sa[4];
#pragma unroll
    for (int t = 0; t < 4; t++) sa[t] = (floatx4){0.f, 0.f, 0.f, 0.f};
    half8 a0 = *(const half8*)&qs[wave * 16 + fr][fc];
    half8 a1 = *(const half8*)&qs[wave * 16 + fr][fc + 32];
#pragma unroll
    for (int t = 0; t < 4; t++) {
        half8 kb0 = *(const half8*)&ks[t * 16 + fr][fc];
        half8 kb1 = *(const half8*)&ks[t * 16 + fr][fc + 32];
        sa[t] = __builtin_amdgcn_mfma_f32_16x16x32_f16(a0, kb0, sa[t], 0, 0, 0);
        sa[t] = __builtin_amdgcn_mfma_f32_16x16x32_f16(a1, kb1, sa[t], 0, 0, 0);
    }

    // softmax over 64 cols; row = wave*16 + (lane>>4)*4 + i
#pragma unroll
    for (int i = 0; i < 4; i++) {
        float mx = -1e30f;
#pragma unroll
        for (int t = 0; t < 4; t++) mx = fmaxf(mx, sa[t][i]);
#pragma unroll
        for (int d = 1; d < 16; d <<= 1) mx = fmaxf(mx, __shfl_xor(mx, d));
        float sum = 0.f;
        float pv[4];
#pragma unroll
        for (int t = 0; t < 4; t++) {
            const float e = __expf((sa[t][i] - mx) * 0.125f);
            pv[t] = e;
            sum += e;
        }
#pragma unroll
        for (int d = 1; d < 16; d <<= 1) sum += __shfl_xor(sum, d);
        const float inv = 1.0f / sum;
        const int prow = ((lane >> 4) << 2) + i;
#pragma unroll
        for (int t = 0; t < 4; t++)
            ps[wave][prow][t * 16 + fr] = (_Float16)(pv[t] * inv);
    }
    // ps[wave] is written+read only by this wave; LDS ops are wave-ordered.

    // PV: O[sq][d] = sum_sk P[sq][sk] * V[sk][d]
    half8 pa0 = *(const half8*)&ps[wave][fr][fc];
    half8 pa1 = *(const half8*)&ps[wave][fr][fc + 32];
    floatx4 oa[4];
#pragma unroll
    for (int t = 0; t < 4; t++) oa[t] = (floatx4){0.f, 0.f, 0.f, 0.f};
#pragma unroll
    for (int t = 0; t < 4; t++) {
        half8 vb0 = *(const half8*)&vt[t * 16 + fr][fc];
        half8 vb1 = *(const half8*)&vt[t * 16 + fr][fc + 32];
        oa[t] = __builtin_amdgcn_mfma_f32_16x16x32_f16(pa0, vb0, oa[t], 0, 0, 0);
        oa[t] = __builtin_amdgcn_mfma_f32_16x16x32_f16(pa1, vb1, oa[t], 0, 0, 0);
    }

    _Float16* obase = out + (size_t)(bb * 64) * 4096 + hh * 64;
#pragma unroll
    for (int t = 0; t < 4; t++)
#pragma unroll
        for (int i = 0; i < 4; i++) {
            const int sq = wave * 16 + ((lane >> 4) << 2) + i;
            obase[(size_t)sq * 4096 + t * 16 + fr] = (_Float16)oa[t][i];
        }
}

// ---------------------------------------------------------------------------
// launcher
// ---------------------------------------------------------------------------
extern "C" void kernel_launch(void* const* d_in, const int* in_sizes, int n_in,
                              void* d_out, int out_size, void* d_ws, size_t ws_size,
                              hipStream_t stream)
{
    const float* x  = (const float*)d_in[0];
    const float* wq = (const float*)d_in[1];
    const float* bq = (const float*)d_in[2];
    const float* wk = (const float*)d_in[3];
    const float* bk = (const float*)d_in[4];
    const float* wv = (const float*)d_in[5];
    const float* bv = (const float*)d_in[6];
    const float* wo = (const float*)d_in[7];
    const float* bo = (const float*)d_in[8];

    const size_t NELT = (size_t)4096 * 4096;            // 16,777,216
    char* ws = (char*)d_ws;
    _Float16* xh      = (_Float16*)(ws);                          // 32 MiB
    _Float16* wcat    = (_Float16*)(ws + 33554432);               // 96 MiB (wq|wk|wv)
    _Float16* woh     = (_Float16*)(ws + 134217728);              // 32 MiB
    _Float16* qkv     = (_Float16*)(ws + 167772160);              // 96 MiB
    _Float16* attnbuf = (_Float16*)(ws + 268435456);              // 32 MiB
    float*    biascat = (float*)(ws + 301989888);                 // 48 KiB

    const dim3 cg(1024), cb(256);
    cast_f16_kernel<<<cg, cb, 0, stream>>>(x,  xh,              (int)NELT);
    cast_f16_kernel<<<cg, cb, 0, stream>>>(wq, wcat,            (int)NELT);
    cast_f16_kernel<<<cg, cb, 0, stream>>>(wk, wcat + NELT,     (int)NELT);
    cast_f16_kernel<<<cg, cb, 0, stream>>>(wv, wcat + 2 * NELT, (int)NELT);
    cast_f16_kernel<<<cg, cb, 0, stream>>>(wo, woh,             (int)NELT);
    hipMemcpyAsync(biascat,        bq, 4096 * sizeof(float), hipMemcpyDeviceToDevice, stream);
    hipMemcpyAsync(biascat + 4096, bk, 4096 * sizeof(float), hipMemcpyDeviceToDevice, stream);
    hipMemcpyAsync(biascat + 8192, bv, 4096 * sizeof(float), hipMemcpyDeviceToDevice, stream);

    // QKV projection: C(4096,12288) = xh @ wcat^T + biascat
    gemm_nt_kernel<1><<<dim3(96, 32), dim3(256), 0, stream>>>(
        xh, wcat, biascat, qkv, 4096, 12288, 4096);

    // fused rope + attention
    attn_kernel<<<dim3(4096), dim3(256), 0, stream>>>(qkv, attnbuf);

    // output projection: d_out(4096,4096) fp32 = attn @ wo^T + bo
    gemm_nt_kernel<0><<<dim3(32, 32), dim3(256), 0, stream>>>(
        attnbuf, woh, bo, d_out, 4096, 4096, 4096);
}

// Round 2
// 1002.965 us; speedup vs baseline: 1.0038x; 1.0038x over previous
//
#include <hip/hip_runtime.h>
#include <cstdint>
#include <cstddef>

// ---------------------------------------------------------------------------
// MultiHeadSelfAttention: x(64,64,4096) fp32; W q/k/v/o (4096,4096); quirky RoPE
// Pipeline: fused cast->f16 | GEMM qkv (M4096,N12288,K4096) | fused rope+attn
//           per (b,h) | GEMM out-proj -> fp32 d_out
// All MFMA f16 16x16x32, fp32 accumulate.
// R2: LDS bank-conflict swizzle in GEMM (staging chunk permutation
//     p = (c + (row>>1)) & 3 -> 2-way max, free per m136), launch merging.
// ---------------------------------------------------------------------------

typedef _Float16 half8 __attribute__((ext_vector_type(8)));
typedef float floatx4 __attribute__((ext_vector_type(4)));

#define NELT_W 16777216u   // 4096*4096
#define NEG_LOG2_10000_OVER_2048 (-0.0064881408103278559f)

// async global->LDS, 16 bytes per lane
__device__ __forceinline__ void gl_lds16(const void* g, void* l) {
    __builtin_amdgcn_global_load_lds(
        (const __attribute__((address_space(1))) void*)(void*)g,
        (__attribute__((address_space(3))) void*)l,
        16, 0, 0);
}

// ---------------------------------------------------------------------------
// fused fp32 -> f16 cast of all 5 tensors: blockIdx.y selects tensor
// ---------------------------------------------------------------------------
__global__ __launch_bounds__(256) void cast5_kernel(
    const float* __restrict__ x,  const float* __restrict__ wq,
    const float* __restrict__ wk, const float* __restrict__ wv,
    const float* __restrict__ wo,
    _Float16* __restrict__ xh, _Float16* __restrict__ wcat,
    _Float16* __restrict__ woh)
{
    const float* s;
    _Float16* d;
    switch (blockIdx.y) {
        case 0:  s = x;  d = xh;                 break;
        case 1:  s = wq; d = wcat;               break;
        case 2:  s = wk; d = wcat + NELT_W;      break;
        case 3:  s = wv; d = wcat + 2 * NELT_W;  break;
        default: s = wo; d = woh;                break;
    }
    int i0 = (blockIdx.x * 256 + threadIdx.x) * 8;
    int stride = gridDim.x * 256 * 8;
    for (int i = i0; i < (int)NELT_W; i += stride) {
        const float4 a = *(const float4*)(s + i);
        const float4 b = *(const float4*)(s + i + 4);
        half8 h;
        h[0] = (_Float16)a.x; h[1] = (_Float16)a.y;
        h[2] = (_Float16)a.z; h[3] = (_Float16)a.w;
        h[4] = (_Float16)b.x; h[5] = (_Float16)b.y;
        h[6] = (_Float16)b.z; h[7] = (_Float16)b.w;
        *(half8*)(d + i) = h;
    }
}

__global__ __launch_bounds__(256) void biascat_kernel(
    const float* __restrict__ bq, const float* __restrict__ bk,
    const float* __restrict__ bv, float* __restrict__ out)
{
    int i = blockIdx.x * 256 + threadIdx.x;
    if (i < 4096) {
        out[i]        = bq[i];
        out[4096 + i] = bk[i];
        out[8192 + i] = bv[i];
    }
}

// ---------------------------------------------------------------------------
// NT GEMM: C[m,n] = sum_k A[m,k]*B[n,k] + bias[n]
// A: MxK f16 row-major, B: NxK f16 row-major. 128x128 tile, BK=32.
// 4 waves, each 64x64 (4x4 tiles of 16x16x32 f16 MFMA).
// LDS layout swizzled: physical chunk slot p holds logical chunk
// c = (p - (row>>1)) & 3, so reads use p = (c + (row>>1)) & 3.
// OUT_F16=1 -> f16 out, else fp32 out.
// ---------------------------------------------------------------------------
template <int OUT_F16>
__global__ __launch_bounds__(256, 2) void gemm_nt_kernel(
    const _Float16* __restrict__ A, const _Float16* __restrict__ B,
    const float* __restrict__ bias, void* __restrict__ Cout,
    int M, int N, int K)
{
    __shared__ __align__(16) _Float16 As[128 * 32];
    __shared__ __align__(16) _Float16 Bs[128 * 32];

    const int tid  = threadIdx.x;
    const int col0 = blockIdx.x * 128;
    const int row0 = blockIdx.y * 128;
    const int wave = tid >> 6;
    const int lane = tid & 63;
    const int wm = (wave >> 1) * 64;   // wave row offset in tile
    const int wn = (wave & 1) * 64;    // wave col offset in tile

    floatx4 zero = {0.f, 0.f, 0.f, 0.f};
    floatx4 acc[4][4];
#pragma unroll
    for (int i = 0; i < 4; i++)
#pragma unroll
        for (int j = 0; j < 4; j++) acc[i][j] = zero;

    // staging: thread t fills phys slot (prow = t>>2, pchunk = t&3) of the
    // k-tile at LDS offset t*16B; it must FETCH logical chunk
    // c = (pchunk - (prow>>1)) & 3. (prow>>1 identical for row and row+64
    // halves since 64>>1 = 32 ≡ 0 mod 4.)
    const int ar = tid >> 2;
    const int ac = (((tid & 3) - (ar >> 1)) & 3) * 8;
    const _Float16* Ag0 = A + (size_t)(row0 + ar) * K + ac;
    const _Float16* Ag1 = A + (size_t)(row0 + 64 + ar) * K + ac;
    const _Float16* Bg0 = B + (size_t)(col0 + ar) * K + ac;
    const _Float16* Bg1 = B + (size_t)(col0 + 64 + ar) * K + ac;
    _Float16* As0 = As + tid * 8;
    _Float16* As1 = As + (tid + 256) * 8;
    _Float16* Bs0 = Bs + tid * 8;
    _Float16* Bs1 = Bs + (tid + 256) * 8;

    const int fr = lane & 15;          // fragment row (m) / col (n)
    const int kc = lane >> 4;          // logical k-chunk (0..3) within BK=32

    for (int kt = 0; kt < K; kt += 32) {
        gl_lds16(Ag0 + kt, As0);
        gl_lds16(Ag1 + kt, As1);
        gl_lds16(Bg0 + kt, Bs0);
        gl_lds16(Bg1 + kt, Bs1);
        __syncthreads();

        half8 af[4], bf[4];
#pragma unroll
        for (int t = 0; t < 4; t++) {
            const int rowa = wm + t * 16 + fr;
            const int rowb = wn + t * 16 + fr;
            const int pa = ((kc + (rowa >> 1)) & 3) * 8;
            const int pb = ((kc + (rowb >> 1)) & 3) * 8;
            af[t] = *(const half8*)(As + (size_t)rowa * 32 + pa);
            bf[t] = *(const half8*)(Bs + (size_t)rowb * 32 + pb);
        }
#pragma unroll
        for (int i = 0; i < 4; i++)
#pragma unroll
            for (int j = 0; j < 4; j++)
                acc[i][j] = __builtin_amdgcn_mfma_f32_16x16x32_f16(
                    af[i], bf[j], acc[i][j], 0, 0, 0);
        __syncthreads();
    }

    // epilogue: C/D layout col=lane&15, row=(lane>>4)*4+reg
    const int crow = row0 + wm + ((lane >> 4) << 2);
    const int ccol = col0 + wn + (lane & 15);
#pragma unroll
    for (int i = 0; i < 4; i++) {
#pragma unroll
        for (int j = 0; j < 4; j++) {
            const int gc = ccol + j * 16;
            const float bv = bias[gc];
#pragma unroll
            for (int r2 = 0; r2 < 4; r2++) {
                const int gr = crow + i * 16 + r2;
                const float v = acc[i][j][r2] + bv;
                if (OUT_F16)
                    ((_Float16*)Cout)[(size_t)gr * N + gc] = (_Float16)v;
                else
                    ((float*)Cout)[(size_t)gr * N + gc] = v;
            }
        }
    }
}

// ---------------------------------------------------------------------------
// Fused rope + attention. One block per (b,h). qkv: (4096, 12288) f16,
// q at col h*64+d, k at 4096+h*64+d, v at 8192+h*64+d. out: (4096,4096) f16.
// RoPE quirk: theta = b * 10000^(-(s*32 + d/2)/2048).
// ---------------------------------------------------------------------------
__global__ __launch_bounds__(256) void attn_kernel(
    const _Float16* __restrict__ qkv, _Float16* __restrict__ out)
{
    __shared__ __align__(16) _Float16 qs[64][72];
    __shared__ __align__(16) _Float16 ks[64][72];
    __shared__ __align__(16) _Float16 vt[64][72];   // vt[d][s_k]
    __shared__ __align__(16) _Float16 ps[4][16][72];

    const int tid  = threadIdx.x;
    const int bb   = blockIdx.x >> 6;   // batch
    const int hh   = blockIdx.x & 63;   // head
    const int wave = tid >> 6;
    const int lane = tid & 63;
    const int r  = tid >> 2;            // row s, 0..63
    const int cb = (tid & 3) * 8;       // col base within 32-chunk
    const float fb = (float)bb;

    const _Float16* grow = qkv + (size_t)(bb * 64 + r) * 12288 + hh * 64;

#pragma unroll
    for (int u = 0; u < 2; u++) {
        const int c8 = cb + u * 32;     // contiguous 32-col chunks per 4-lane group
        half8 q8 = *(const half8*)(grow + c8);
        half8 k8 = *(const half8*)(grow + 4096 + c8);
        half8 v8 = *(const half8*)(grow + 8192 + c8);
#pragma unroll
        for (int p = 0; p < 4; p++) {
            const int m = r * 32 + (c8 >> 1) + p;
            const float theta = fb * exp2f((float)m * NEG_LOG2_10000_OVER_2048);
            float sn, cs;
            __sincosf(theta, &sn, &cs);
            const float qe = (float)q8[2 * p], qo = (float)q8[2 * p + 1];
            q8[2 * p]     = (_Float16)(qe * cs - qo * sn);
            q8[2 * p + 1] = (_Float16)(qe * sn + qo * cs);
            const float ke = (float)k8[2 * p], ko = (float)k8[2 * p + 1];
            k8[2 * p]     = (_Float16)(ke * cs - ko * sn);
            k8[2 * p + 1] = (_Float16)(ke * sn + ko * cs);
        }
        *(half8*)&qs[r][c8] = q8;
        *(half8*)&ks[r][c8] = k8;
#pragma unroll
        for (int j = 0; j < 8; j++) vt[c8 + j][r] = v8[j];
    }
    __syncthreads();

    const int fr = lane & 15;
    const int fc = (lane >> 4) * 8;

    // scores: wave handles rows sq in [wave*16, wave*16+16), all 64 cols
    floatx4 sa[4];
#pragma unroll
    for (int t = 0; t < 4; t++) sa[t] = (floatx4){0.f, 0.f, 0.f, 0.f};
    half8 a0 = *(const half8*)&qs[wave * 16 + fr][fc];
    half8 a1 = *(const half8*)&qs[wave * 16 + fr][fc + 32];
#pragma unroll
    for (int t = 0; t < 4; t++) {
        half8 kb0 = *(const half8*)&ks[t * 16 + fr][fc];
        half8 kb1 = *(const half8*)&ks[t * 16 + fr][fc + 32];
        sa[t] = __builtin_amdgcn_mfma_f32_16x16x32_f16(a0, kb0, sa[t], 0, 0, 0);
        sa[t] = __builtin_amdgcn_mfma_f32_16x16x32_f16(a1, kb1, sa[t], 0, 0, 0);
    }

    // softmax over 64 cols; row = wave*16 + (lane>>4)*4 + i
#pragma unroll
    for (int i = 0; i < 4; i++) {
        float mx = -1e30f;
#pragma unroll
        for (int t = 0; t < 4; t++) mx = fmaxf(mx, sa[t][i]);
#pragma unroll
        for (int d = 1; d < 16; d <<= 1) mx = fmaxf(mx, __shfl_xor(mx, d));
        float sum = 0.f;
        float pv[4];
#pragma unroll
        for (int t = 0; t < 4; t++) {
            const float e = __expf((sa[t][i] - mx) * 0.125f);
            pv[t] = e;
            sum += e;
        }
#pragma unroll
        for (int d = 1; d < 16; d <<= 1) sum += __shfl_xor(sum, d);
        const float inv = 1.0f / sum;
        const int prow = ((lane >> 4) << 2) + i;
#pragma unroll
        for (int t = 0; t < 4; t++)
            ps[wave][prow][t * 16 + fr] = (_Float16)(pv[t] * inv);
    }
    // ps[wave] is written+read only by this wave; LDS ops are wave-ordered.

    // PV: O[sq][d] = sum_sk P[sq][sk] * V[sk][d]
    half8 pa0 = *(const half8*)&ps[wave][fr][fc];
    half8 pa1 = *(const half8*)&ps[wave][fr][fc + 32];
    floatx4 oa[4];
#pragma unroll
    for (int t = 0; t < 4; t++) oa[t] = (floatx4){0.f, 0.f, 0.f, 0.f};
#pragma unroll
    for (int t = 0; t < 4; t++) {
        half8 vb0 = *(const half8*)&vt[t * 16 + fr][fc];
        half8 vb1 = *(const half8*)&vt[t * 16 + fr][fc + 32];
        oa[t] = __builtin_amdgcn_mfma_f32_16x16x32_f16(pa0, vb0, oa[t], 0, 0, 0);
        oa[t] = __builtin_amdgcn_mfma_f32_16x16x32_f16(pa1, vb1, oa[t], 0, 0, 0);
    }

    _Float16* obase = out + (size_t)(bb * 64) * 4096 + hh * 64;
#pragma unroll
    for (int t = 0; t < 4; t++)
#pragma unroll
        for (int i = 0; i < 4; i++) {
            const int sq = wave * 16 + ((lane >> 4) << 2) + i;
            obase[(size_t)sq * 4096 + t * 16 + fr] = (_Float16)oa[t][i];
        }
}

// ---------------------------------------------------------------------------
// launcher
// ---------------------------------------------------------------------------
extern "C" void kernel_launch(void* const* d_in, const int* in_sizes, int n_in,
                              void* d_out, int out_size, void* d_ws, size_t ws_size,
                              hipStream_t stream)
{
    const float* x  = (const float*)d_in[0];
    const float* wq = (const float*)d_in[1];
    const float* bq = (const float*)d_in[2];
    const float* wk = (const float*)d_in[3];
    const float* bk = (const float*)d_in[4];
    const float* wv = (const float*)d_in[5];
    const float* bv = (const float*)d_in[6];
    const float* wo = (const float*)d_in[7];
    const float* bo = (const float*)d_in[8];

    const size_t NELT = (size_t)4096 * 4096;            // 16,777,216
    char* ws = (char*)d_ws;
    _Float16* xh      = (_Float16*)(ws);                          // 32 MiB
    _Float16* wcat    = (_Float16*)(ws + 33554432);               // 96 MiB (wq|wk|wv)
    _Float16* woh     = (_Float16*)(ws + 134217728);              // 32 MiB
    _Float16* qkv     = (_Float16*)(ws + 167772160);              // 96 MiB
    _Float16* attnbuf = (_Float16*)(ws + 268435456);              // 32 MiB
    float*    biascat = (float*)(ws + 301989888);                 // 48 KiB

    cast5_kernel<<<dim3(1024, 5), dim3(256), 0, stream>>>(
        x, wq, wk, wv, wo, xh, wcat, woh);
    biascat_kernel<<<dim3(16), dim3(256), 0, stream>>>(bq, bk, bv, biascat);

    // QKV projection: C(4096,12288) = xh @ wcat^T + biascat
    gemm_nt_kernel<1><<<dim3(96, 32), dim3(256), 0, stream>>>(
        xh, wcat, biascat, qkv, 4096, 12288, 4096);

    // fused rope + attention
    attn_kernel<<<dim3(4096), dim3(256), 0, stream>>>(qkv, attnbuf);

    // output projection: d_out(4096,4096) fp32 = attn @ wo^T + bo
    gemm_nt_kernel<0><<<dim3(32, 32), dim3(256), 0, stream>>>(
        attnbuf, woh, bo, d_out, 4096, 4096, 4096);
}